// Round 1
// baseline (122.408 us; speedup 1.0000x reference)
//
#include <hip/hip_runtime.h>
#include <math.h>

#define BB 64
#define LL 512
#define HH 768
#define SS 32
#define EPS_LN 1e-12f
#define EPS_COS 1e-8f

// ---------------- Kernel 1: ragged mean + LN(g2,b2) -> sel[B,H], selnorm[B] ----
__global__ __launch_bounds__(256) void k_segmean(
    const float* __restrict__ hs,     // [B,L,H]
    const float* __restrict__ g2, const float* __restrict__ b2,
    const int* __restrict__ gstart, const int* __restrict__ gend,
    float* __restrict__ sel,          // [B,H]
    float* __restrict__ selnorm)      // [B]
{
    const int b = blockIdx.x;
    const int tid = threadIdx.x;
    const int s0 = gstart[b];
    const int e0 = gend[b];
    const float cnt = fmaxf((float)(e0 - s0), 1.0f);

    float a0 = 0.f, a1 = 0.f, a2 = 0.f;
    const float* base = hs + (size_t)b * LL * HH;
    for (int l = s0; l < e0; ++l) {
        const float* row = base + (size_t)l * HH;
        a0 += row[tid];
        a1 += row[tid + 256];
        a2 += row[tid + 512];
    }
    const float inv = 1.0f / cnt;
    const float v0 = a0 * inv, v1 = a1 * inv, v2 = a2 * inv;

    // block reduce: sum and sumsq over H
    float s = v0 + v1 + v2;
    float q = v0 * v0 + v1 * v1 + v2 * v2;
    for (int o = 32; o > 0; o >>= 1) {
        s += __shfl_down(s, o, 64);
        q += __shfl_down(q, o, 64);
    }
    __shared__ float ps[4], pq[4], pn[4];
    __shared__ float sh_mu, sh_rinv;
    const int lane = tid & 63, wid = tid >> 6;
    if (lane == 0) { ps[wid] = s; pq[wid] = q; }
    __syncthreads();
    if (tid == 0) {
        float ts = ps[0] + ps[1] + ps[2] + ps[3];
        float tq = pq[0] + pq[1] + pq[2] + pq[3];
        float mu = ts / (float)HH;
        float var = tq / (float)HH - mu * mu;
        sh_mu = mu;
        sh_rinv = rsqrtf(var + EPS_LN);
    }
    __syncthreads();
    const float mu = sh_mu, rinv = sh_rinv;
    const float y0 = (v0 - mu) * rinv * g2[tid]       + b2[tid];
    const float y1 = (v1 - mu) * rinv * g2[tid + 256] + b2[tid + 256];
    const float y2 = (v2 - mu) * rinv * g2[tid + 512] + b2[tid + 512];
    sel[b * HH + tid]       = y0;
    sel[b * HH + tid + 256] = y1;
    sel[b * HH + tid + 512] = y2;

    float n = y0 * y0 + y1 * y1 + y2 * y2;
    for (int o = 32; o > 0; o >>= 1) n += __shfl_down(n, o, 64);
    if (lane == 0) pn[wid] = n;
    __syncthreads();
    if (tid == 0) selnorm[b] = sqrtf(pn[0] + pn[1] + pn[2] + pn[3]);
}

// ---------------- Kernel 2: fused GEMM + LN(g1,b1) + cosine --------------------
// grid = (B*S)/R blocks, R=8 rows per block, 768 threads (1 output col h each).
#define RR 8
__global__ __launch_bounds__(768) void k_main(
    const float* __restrict__ gp,     // [B*S, H]
    const float* __restrict__ W,      // [H, H] row-major, t[h] = sum_k x[k]*W[h,k]
    const float* __restrict__ bias,   // [H]
    const float* __restrict__ g1, const float* __restrict__ b1,
    const float* __restrict__ sel,    // [B,H]
    const float* __restrict__ selnorm,// [B]
    float* __restrict__ out)          // [B*S]
{
    const int tid = threadIdx.x;
    const int rowbase = blockIdx.x * RR;
    const int b = rowbase / SS;        // 8 | 32, block never crosses batch

    __shared__ __align__(16) float xs[RR][HH];   // 24 KB
    {
        const float4* src = (const float4*)(gp + (size_t)rowbase * HH);
        float4* dst = (float4*)&xs[0][0];
        for (int i = tid; i < RR * HH / 4; i += 768) dst[i] = src[i];
    }
    __syncthreads();

    const int h = tid;
    float acc[RR];
#pragma unroll
    for (int r = 0; r < RR; ++r) acc[r] = 0.f;

    const float* wrow = W + (size_t)h * HH;
    for (int k = 0; k < HH; k += 4) {
        const float4 wv = *(const float4*)(wrow + k);
#pragma unroll
        for (int r = 0; r < RR; ++r) {
            const float4 xv = *(const float4*)&xs[r][k];
            acc[r] += wv.x * xv.x + wv.y * xv.y + wv.z * xv.z + wv.w * xv.w;
        }
    }

    float t[RR];
    const float bh = bias[h];
#pragma unroll
    for (int r = 0; r < RR; ++r) t[r] = acc[r] + bh;

    // per-row LN stats: sum, sumsq over 768 threads for each r
    __shared__ float rs[12][RR], rq[12][RR];
    __shared__ float mu_s[RR], rinv_s[RR];
    const int lane = tid & 63, wid = tid >> 6;
#pragma unroll
    for (int r = 0; r < RR; ++r) {
        float s = t[r];
        float q = t[r] * t[r];
        for (int o = 32; o > 0; o >>= 1) {
            s += __shfl_down(s, o, 64);
            q += __shfl_down(q, o, 64);
        }
        if (lane == 0) { rs[wid][r] = s; rq[wid][r] = q; }
    }
    __syncthreads();
    if (tid < RR) {
        float s = 0.f, q = 0.f;
        for (int w = 0; w < 12; ++w) { s += rs[w][tid]; q += rq[w][tid]; }
        const float mu = s / (float)HH;
        const float var = q / (float)HH - mu * mu;
        mu_s[tid] = mu;
        rinv_s[tid] = rsqrtf(var + EPS_LN);
    }
    __syncthreads();

    const float g = g1[h], bb = b1[h];
    const float se = sel[b * HH + h];
    float yd[RR], yq[RR];
#pragma unroll
    for (int r = 0; r < RR; ++r) {
        const float y = (t[r] - mu_s[r]) * rinv_s[r] * g + bb;
        yd[r] = y * se;
        yq[r] = y * y;
    }
    __shared__ float rd2[12][RR], rq2[12][RR];
#pragma unroll
    for (int r = 0; r < RR; ++r) {
        float d = yd[r];
        float q = yq[r];
        for (int o = 32; o > 0; o >>= 1) {
            d += __shfl_down(d, o, 64);
            q += __shfl_down(q, o, 64);
        }
        if (lane == 0) { rd2[wid][r] = d; rq2[wid][r] = q; }
    }
    __syncthreads();
    if (tid < RR) {
        float d = 0.f, q = 0.f;
        for (int w = 0; w < 12; ++w) { d += rd2[w][tid]; q += rq2[w][tid]; }
        const float ny = sqrtf(q);
        out[rowbase + tid] = d / fmaxf(selnorm[b] * ny, EPS_COS);
    }
}

extern "C" void kernel_launch(void* const* d_in, const int* in_sizes, int n_in,
                              void* d_out, int out_size, void* d_ws, size_t ws_size,
                              hipStream_t stream) {
    const float* hs  = (const float*)d_in[0];   // [B,L,H]
    const float* gp  = (const float*)d_in[1];   // [B*S,H]
    const float* W   = (const float*)d_in[2];   // [H,H]
    const float* bia = (const float*)d_in[3];   // [H]
    const float* g1  = (const float*)d_in[4];
    const float* b1  = (const float*)d_in[5];
    const float* g2  = (const float*)d_in[6];
    const float* b2  = (const float*)d_in[7];
    const int* gs    = (const int*)d_in[8];     // [B]
    const int* ge    = (const int*)d_in[9];     // [B]
    float* out = (float*)d_out;

    float* sel     = (float*)d_ws;                    // B*H floats
    float* selnorm = sel + (size_t)BB * HH;           // B floats

    k_segmean<<<BB, 256, 0, stream>>>(hs, g2, b2, gs, ge, sel, selnorm);
    k_main<<<(BB * SS) / RR, 768, 0, stream>>>(gp, W, bia, g1, b1, sel, selnorm, out);
}

// Round 2
// 112.296 us; speedup vs baseline: 1.0901x; 1.0901x over previous
//
#include <hip/hip_runtime.h>
#include <math.h>

#define BB 64
#define LL 512
#define HH 768
#define SS 32
#define EPS_LN 1e-12f
#define EPS_COS 1e-8f

// ---------------- Kernel 1: ragged mean + LN(g2,b2) -> sel[B,H], selnorm[B] ----
// 768 threads: thread = column h. Unrolled independent accumulators to pipeline loads.
__global__ __launch_bounds__(768) void k_segmean(
    const float* __restrict__ hs,     // [B,L,H]
    const float* __restrict__ g2, const float* __restrict__ b2,
    const int* __restrict__ gstart, const int* __restrict__ gend,
    float* __restrict__ sel,          // [B,H]
    float* __restrict__ selnorm)      // [B]
{
    const int b = blockIdx.x;
    const int tid = threadIdx.x;      // = h
    const int s0 = gstart[b];
    const int e0 = gend[b];
    const float cnt = fmaxf((float)(e0 - s0), 1.0f);

    const float* base = hs + (size_t)b * LL * HH + tid;
    float a0 = 0.f, a1 = 0.f, a2 = 0.f, a3 = 0.f;
    int l = s0;
    for (; l + 4 <= e0; l += 4) {
        a0 += base[(size_t)(l + 0) * HH];
        a1 += base[(size_t)(l + 1) * HH];
        a2 += base[(size_t)(l + 2) * HH];
        a3 += base[(size_t)(l + 3) * HH];
    }
    for (; l < e0; ++l) a0 += base[(size_t)l * HH];
    const float v = ((a0 + a1) + (a2 + a3)) / cnt;

    // block reduce over 768 threads (12 waves): sum and sumsq
    float s = v, q = v * v;
    for (int o = 32; o > 0; o >>= 1) {
        s += __shfl_down(s, o, 64);
        q += __shfl_down(q, o, 64);
    }
    __shared__ float ps[12], pq[12], pn[12];
    __shared__ float sh_mu, sh_rinv;
    const int lane = tid & 63, wid = tid >> 6;
    if (lane == 0) { ps[wid] = s; pq[wid] = q; }
    __syncthreads();
    if (tid == 0) {
        float ts = 0.f, tq = 0.f;
        for (int w = 0; w < 12; ++w) { ts += ps[w]; tq += pq[w]; }
        float mu = ts / (float)HH;
        float var = tq / (float)HH - mu * mu;
        sh_mu = mu;
        sh_rinv = rsqrtf(var + EPS_LN);
    }
    __syncthreads();
    const float y = (v - sh_mu) * sh_rinv * g2[tid] + b2[tid];
    sel[b * HH + tid] = y;

    float n = y * y;
    for (int o = 32; o > 0; o >>= 1) n += __shfl_down(n, o, 64);
    if (lane == 0) pn[wid] = n;
    __syncthreads();
    if (tid == 0) {
        float t = 0.f;
        for (int w = 0; w < 12; ++w) t += pn[w];
        selnorm[b] = sqrtf(t);
    }
}

// ---------------- Kernel 2: fused GEMM + LN(g1,b1) + cosine --------------------
// grid = (B*S)/RR blocks, RR=8 rows per block, 768 threads (1 output col h each).
// x is block-uniform -> read via uniform global addresses (compiler emits s_load,
// scalar pipe), W via per-thread float4 vector loads (L2-resident, 2.25 MB).
// No LDS in the main loop: VALU issues nearly pure v_fma_f32.
#define RR 8
__global__ __launch_bounds__(768) void k_main(
    const float* __restrict__ gp,     // [B*S, H]
    const float* __restrict__ W,      // [H, H] row-major, t[h] = sum_k x[k]*W[h,k]
    const float* __restrict__ bias,   // [H]
    const float* __restrict__ g1, const float* __restrict__ b1,
    const float* __restrict__ sel,    // [B,H]
    const float* __restrict__ selnorm,// [B]
    float* __restrict__ out)          // [B*S]
{
    const int tid = threadIdx.x;
    const int rowbase = blockIdx.x * RR;
    const int b = rowbase / SS;        // 8 | 32, block never crosses batch
    const int h = tid;

    const float* __restrict__ xbase = gp + (size_t)rowbase * HH;  // block-uniform
    const float* __restrict__ wrow = W + (size_t)h * HH;

    float acc[RR];
#pragma unroll
    for (int r = 0; r < RR; ++r) acc[r] = 0.f;

    for (int k = 0; k < HH; k += 4) {
        const float4 wv = *(const float4*)(wrow + k);
#pragma unroll
        for (int r = 0; r < RR; ++r) {
            const float4 xv = *(const float4*)(xbase + (size_t)r * HH + k);  // uniform -> s_load
            acc[r] = fmaf(wv.x, xv.x, acc[r]);
            acc[r] = fmaf(wv.y, xv.y, acc[r]);
            acc[r] = fmaf(wv.z, xv.z, acc[r]);
            acc[r] = fmaf(wv.w, xv.w, acc[r]);
        }
    }

    float t[RR];
    const float bh = bias[h];
#pragma unroll
    for (int r = 0; r < RR; ++r) t[r] = acc[r] + bh;

    // per-row LN stats: sum, sumsq over 768 threads for each r
    __shared__ float rs[12][RR], rq[12][RR];
    __shared__ float mu_s[RR], rinv_s[RR];
    const int lane = tid & 63, wid = tid >> 6;
#pragma unroll
    for (int r = 0; r < RR; ++r) {
        float s = t[r];
        float q = t[r] * t[r];
        for (int o = 32; o > 0; o >>= 1) {
            s += __shfl_down(s, o, 64);
            q += __shfl_down(q, o, 64);
        }
        if (lane == 0) { rs[wid][r] = s; rq[wid][r] = q; }
    }
    __syncthreads();
    if (tid < RR) {
        float s = 0.f, q = 0.f;
        for (int w = 0; w < 12; ++w) { s += rs[w][tid]; q += rq[w][tid]; }
        const float mu = s / (float)HH;
        const float var = q / (float)HH - mu * mu;
        mu_s[tid] = mu;
        rinv_s[tid] = rsqrtf(var + EPS_LN);
    }
    __syncthreads();

    const float g = g1[h], bb = b1[h];
    const float se = sel[b * HH + h];
    float yd[RR], yq[RR];
#pragma unroll
    for (int r = 0; r < RR; ++r) {
        const float y = (t[r] - mu_s[r]) * rinv_s[r] * g + bb;
        yd[r] = y * se;
        yq[r] = y * y;
    }
    __shared__ float rd2[12][RR], rq2[12][RR];
#pragma unroll
    for (int r = 0; r < RR; ++r) {
        float d = yd[r];
        float q = yq[r];
        for (int o = 32; o > 0; o >>= 1) {
            d += __shfl_down(d, o, 64);
            q += __shfl_down(q, o, 64);
        }
        if (lane == 0) { rd2[wid][r] = d; rq2[wid][r] = q; }
    }
    __syncthreads();
    if (tid < RR) {
        float d = 0.f, q = 0.f;
        for (int w = 0; w < 12; ++w) { d += rd2[w][tid]; q += rq2[w][tid]; }
        const float ny = sqrtf(q);
        out[rowbase + tid] = d / fmaxf(selnorm[b] * ny, EPS_COS);
    }
}

extern "C" void kernel_launch(void* const* d_in, const int* in_sizes, int n_in,
                              void* d_out, int out_size, void* d_ws, size_t ws_size,
                              hipStream_t stream) {
    const float* hs  = (const float*)d_in[0];   // [B,L,H]
    const float* gp  = (const float*)d_in[1];   // [B*S,H]
    const float* W   = (const float*)d_in[2];   // [H,H]
    const float* bia = (const float*)d_in[3];   // [H]
    const float* g1  = (const float*)d_in[4];
    const float* b1  = (const float*)d_in[5];
    const float* g2  = (const float*)d_in[6];
    const float* b2  = (const float*)d_in[7];
    const int* gs    = (const int*)d_in[8];     // [B]
    const int* ge    = (const int*)d_in[9];     // [B]
    float* out = (float*)d_out;

    float* sel     = (float*)d_ws;                    // B*H floats
    float* selnorm = sel + (size_t)BB * HH;           // B floats

    k_segmean<<<BB, 768, 0, stream>>>(hs, g2, b2, gs, ge, sel, selnorm);
    k_main<<<(BB * SS) / RR, 768, 0, stream>>>(gp, W, bia, g1, b1, sel, selnorm, out);
}

// Round 3
// 97.890 us; speedup vs baseline: 1.2505x; 1.1472x over previous
//
#include <hip/hip_runtime.h>
#include <math.h>

#define BB 64
#define LL 512
#define HH 768
#define SS 32
#define MM 2048            // B*S rows
#define EPS_LN 1e-12f
#define EPS_COS 1e-8f

// GEMM tiling
#define BM 64
#define BN 96
#define KT 32
#define KTP 36             // padded k-stride (16B-aligned rows, spreads banks)
#define NKS (HH / KT)      // 24
#define GRID_M (MM / BM)   // 32
#define GRID_N (HH / BN)   // 8
#define NGEMM (GRID_M * GRID_N)  // 256

// Fused kernel: blocks [0,256) do the GEMM t = gp @ W^T + b (write t to ws);
// blocks [256,320) do the ragged segment-mean + LN(g2,b2) -> sel, selnorm.
__global__ __launch_bounds__(256) void k_gemm_seg(
    const float* __restrict__ gp,   // [MM, HH]
    const float* __restrict__ Wm,   // [HH, HH] row-major; t[m][n] = sum_k gp[m][k]*Wm[n][k]
    const float* __restrict__ bias, // [HH]
    const float* __restrict__ hs,   // [BB, LL, HH]
    const float* __restrict__ g2, const float* __restrict__ b2,
    const int* __restrict__ gstart, const int* __restrict__ gend,
    float* __restrict__ tbuf,       // [MM, HH]
    float* __restrict__ sel,        // [BB, HH]
    float* __restrict__ selnorm)    // [BB]
{
    __shared__ __align__(16) float Xs[2][BM][KTP];   // 18.4 KB
    __shared__ __align__(16) float Wsh[2][BN][KTP];  // 27.6 KB
    __shared__ float red[3][4];
    __shared__ float sh2[2];

    const int bid = blockIdx.x;
    const int t = threadIdx.x;

    if (bid < NGEMM) {
        // consecutive bids share the same W n-tile (bm fastest) for L2 reuse
        const int bm = (bid & (GRID_M - 1)) * BM;
        const int bn = (bid / GRID_M) * BN;
        const int tc = t & 15;     // cols 6*tc .. 6*tc+5
        const int tr = t >> 4;     // rows 4*tr .. 4*tr+3

        // staging: X tile 64x32 = 512 float4 (2/thread), W tile 96x32 = 768 float4 (3/thread)
        const int r0 = t >> 3;            // 0..31
        const int r1 = r0 + 32;           // 32..63
        const int r2 = r0 + 64;           // 64..95 (W only)
        const int k4 = (t & 7) * 4;       // 0..28

        const float* gpx = gp + (size_t)bm * HH;
        const float* wmx = Wm + (size_t)bn * HH;

        float4 xf0, xf1, wf0, wf1, wf2;
        // prologue: stage step 0 into buf 0
        xf0 = *(const float4*)(gpx + (size_t)r0 * HH + k4);
        xf1 = *(const float4*)(gpx + (size_t)r1 * HH + k4);
        wf0 = *(const float4*)(wmx + (size_t)r0 * HH + k4);
        wf1 = *(const float4*)(wmx + (size_t)r1 * HH + k4);
        wf2 = *(const float4*)(wmx + (size_t)r2 * HH + k4);
        *(float4*)&Xs[0][r0][k4] = xf0;
        *(float4*)&Xs[0][r1][k4] = xf1;
        *(float4*)&Wsh[0][r0][k4] = wf0;
        *(float4*)&Wsh[0][r1][k4] = wf1;
        *(float4*)&Wsh[0][r2][k4] = wf2;
        __syncthreads();

        float acc[4][6];
#pragma unroll
        for (int r = 0; r < 4; ++r)
#pragma unroll
            for (int c = 0; c < 6; ++c) acc[r][c] = 0.f;

        for (int s = 0; s < NKS; ++s) {
            const int cur = s & 1;
            // T14: issue next-tile global loads early, write to LDS after compute
            if (s + 1 < NKS) {
                const int kn = (s + 1) * KT;
                xf0 = *(const float4*)(gpx + (size_t)r0 * HH + kn + k4);
                xf1 = *(const float4*)(gpx + (size_t)r1 * HH + kn + k4);
                wf0 = *(const float4*)(wmx + (size_t)r0 * HH + kn + k4);
                wf1 = *(const float4*)(wmx + (size_t)r1 * HH + kn + k4);
                wf2 = *(const float4*)(wmx + (size_t)r2 * HH + kn + k4);
            }
            const float (*Xc)[KTP] = Xs[cur];
            const float (*Wc)[KTP] = Wsh[cur];
#pragma unroll
            for (int g = 0; g < KT / 4; ++g) {
                float4 xv[4], wv[6];
#pragma unroll
                for (int r = 0; r < 4; ++r)
                    xv[r] = *(const float4*)&Xc[4 * tr + r][4 * g];
#pragma unroll
                for (int c = 0; c < 6; ++c)
                    wv[c] = *(const float4*)&Wc[6 * tc + c][4 * g];
#pragma unroll
                for (int r = 0; r < 4; ++r)
#pragma unroll
                    for (int c = 0; c < 6; ++c) {
                        acc[r][c] = fmaf(xv[r].x, wv[c].x, acc[r][c]);
                        acc[r][c] = fmaf(xv[r].y, wv[c].y, acc[r][c]);
                        acc[r][c] = fmaf(xv[r].z, wv[c].z, acc[r][c]);
                        acc[r][c] = fmaf(xv[r].w, wv[c].w, acc[r][c]);
                    }
            }
            if (s + 1 < NKS) {
                const int nxt = cur ^ 1;
                *(float4*)&Xs[nxt][r0][k4] = xf0;
                *(float4*)&Xs[nxt][r1][k4] = xf1;
                *(float4*)&Wsh[nxt][r0][k4] = wf0;
                *(float4*)&Wsh[nxt][r1][k4] = wf1;
                *(float4*)&Wsh[nxt][r2][k4] = wf2;
            }
            __syncthreads();
        }

        // epilogue: t = acc + bias
#pragma unroll
        for (int c = 0; c < 6; ++c) {
            const int n = bn + 6 * tc + c;
            const float bv = bias[n];
#pragma unroll
            for (int r = 0; r < 4; ++r)
                tbuf[(size_t)(bm + 4 * tr + r) * HH + n] = acc[r][c] + bv;
        }
    } else {
        // ---------------- segment mean + LN(g2,b2) ----------------
        const int b = bid - NGEMM;
        const int s0 = gstart[b], e0 = gend[b];
        const float inv = 1.0f / fmaxf((float)(e0 - s0), 1.0f);
        const float* base = hs + (size_t)b * LL * HH;
        const int c0 = t, c1 = t + 256, c2 = t + 512;

        float a[3][4];
#pragma unroll
        for (int j = 0; j < 3; ++j)
#pragma unroll
            for (int u = 0; u < 4; ++u) a[j][u] = 0.f;
        int l = s0;
        for (; l + 4 <= e0; l += 4) {
#pragma unroll
            for (int u = 0; u < 4; ++u) {
                const float* row = base + (size_t)(l + u) * HH;
                a[0][u] += row[c0];
                a[1][u] += row[c1];
                a[2][u] += row[c2];
            }
        }
        for (; l < e0; ++l) {
            const float* row = base + (size_t)l * HH;
            a[0][0] += row[c0];
            a[1][0] += row[c1];
            a[2][0] += row[c2];
        }
        float v0 = (a[0][0] + a[0][1] + a[0][2] + a[0][3]) * inv;
        float v1 = (a[1][0] + a[1][1] + a[1][2] + a[1][3]) * inv;
        float v2 = (a[2][0] + a[2][1] + a[2][2] + a[2][3]) * inv;

        float s = v0 + v1 + v2;
        float q = v0 * v0 + v1 * v1 + v2 * v2;
        for (int o = 32; o > 0; o >>= 1) {
            s += __shfl_down(s, o, 64);
            q += __shfl_down(q, o, 64);
        }
        const int lane = t & 63, wid = t >> 6;
        if (lane == 0) { red[0][wid] = s; red[1][wid] = q; }
        __syncthreads();
        if (t == 0) {
            float ts = red[0][0] + red[0][1] + red[0][2] + red[0][3];
            float tq = red[1][0] + red[1][1] + red[1][2] + red[1][3];
            float mu = ts / (float)HH;
            float var = tq / (float)HH - mu * mu;
            sh2[0] = mu;
            sh2[1] = rsqrtf(var + EPS_LN);
        }
        __syncthreads();
        const float mu = sh2[0], rinv = sh2[1];
        const float y0 = (v0 - mu) * rinv * g2[c0] + b2[c0];
        const float y1 = (v1 - mu) * rinv * g2[c1] + b2[c1];
        const float y2 = (v2 - mu) * rinv * g2[c2] + b2[c2];
        sel[b * HH + c0] = y0;
        sel[b * HH + c1] = y1;
        sel[b * HH + c2] = y2;
        float n = y0 * y0 + y1 * y1 + y2 * y2;
        for (int o = 32; o > 0; o >>= 1) n += __shfl_down(n, o, 64);
        if (lane == 0) red[2][wid] = n;
        __syncthreads();
        if (t == 0) selnorm[b] = sqrtf(red[2][0] + red[2][1] + red[2][2] + red[2][3]);
    }
}

// Epilogue: one wave per t-row. LN(g1,b1) + cosine vs sel. Shuffle-only reductions.
__global__ __launch_bounds__(512) void k_finish(
    const float* __restrict__ tbuf,  // [MM, HH]
    const float* __restrict__ g1, const float* __restrict__ b1,
    const float* __restrict__ sel,   // [BB, HH]
    const float* __restrict__ selnorm,
    float* __restrict__ out)         // [MM]
{
    const int lane = threadIdx.x & 63;
    const int w = threadIdx.x >> 6;
    const int m = blockIdx.x * 8 + w;     // 256 blocks * 8 waves = 2048 rows
    const int b = m >> 5;                 // row / SS
    const float* trow = tbuf + (size_t)m * HH;

    float v[12];
#pragma unroll
    for (int j = 0; j < 12; ++j) v[j] = trow[lane + 64 * j];

    float s = 0.f, q = 0.f;
#pragma unroll
    for (int j = 0; j < 12; ++j) { s += v[j]; q = fmaf(v[j], v[j], q); }
    for (int o = 32; o > 0; o >>= 1) {
        s += __shfl_xor(s, o, 64);
        q += __shfl_xor(q, o, 64);
    }
    const float mu = s * (1.0f / (float)HH);
    const float var = q * (1.0f / (float)HH) - mu * mu;
    const float rinv = rsqrtf(var + EPS_LN);

    const float* selb = sel + (size_t)b * HH;
    float d = 0.f, n2 = 0.f;
#pragma unroll
    for (int j = 0; j < 12; ++j) {
        const int col = lane + 64 * j;
        const float y = (v[j] - mu) * rinv * g1[col] + b1[col];
        d = fmaf(y, selb[col], d);
        n2 = fmaf(y, y, n2);
    }
    for (int o = 32; o > 0; o >>= 1) {
        d += __shfl_xor(d, o, 64);
        n2 += __shfl_xor(n2, o, 64);
    }
    if (lane == 0)
        out[m] = d / fmaxf(selnorm[b] * sqrtf(n2), EPS_COS);
}

extern "C" void kernel_launch(void* const* d_in, const int* in_sizes, int n_in,
                              void* d_out, int out_size, void* d_ws, size_t ws_size,
                              hipStream_t stream) {
    const float* hs  = (const float*)d_in[0];   // [B,L,H]
    const float* gp  = (const float*)d_in[1];   // [B*S,H]
    const float* W   = (const float*)d_in[2];   // [H,H]
    const float* bia = (const float*)d_in[3];   // [H]
    const float* g1  = (const float*)d_in[4];
    const float* b1  = (const float*)d_in[5];
    const float* g2  = (const float*)d_in[6];
    const float* b2  = (const float*)d_in[7];
    const int* gs    = (const int*)d_in[8];     // [B]
    const int* ge    = (const int*)d_in[9];     // [B]
    float* out = (float*)d_out;

    float* tbuf    = (float*)d_ws;                       // MM*HH floats (6.29 MB)
    float* sel     = tbuf + (size_t)MM * HH;             // BB*HH floats
    float* selnorm = sel + (size_t)BB * HH;              // BB floats

    k_gemm_seg<<<NGEMM + BB, 256, 0, stream>>>(gp, W, bia, hs, g2, b2, gs, ge,
                                               tbuf, sel, selnorm);
    k_finish<<<MM / 8, 512, 0, stream>>>(tbuf, g1, b1, sel, selnorm, out);
}

// Round 4
// 39.233 us; speedup vs baseline: 3.1200x; 2.4951x over previous
//
#include <hip/hip_runtime.h>
#include <hip/hip_bf16.h>
#include <math.h>

#define BB 64
#define LL 512
#define HH 768
#define SS 32
#define MM 2048
#define EPS_LN 1e-12f
#define EPS_COS 1e-8f

#define NKS 24                  // k-steps of 32
#define A_FRAGS (128 * NKS)     // (2048/16) m-groups * 24
#define B_FRAGS (48 * NKS)      // (768/16) n-groups * 24
#define NGPB 768                // A_FRAGS*64/256
#define NWB 288                 // B_FRAGS*64/256
#define CH_PER_G (NKS * 2 * 64) // short8 chunks per row-group: 3072

typedef __attribute__((ext_vector_type(8))) short short8;
typedef __attribute__((ext_vector_type(4))) float f32x4;

static __device__ inline unsigned short f2bf(float x) {
    __hip_bfloat16 h = __float2bfloat16(x);
    unsigned short b; __builtin_memcpy(&b, &h, 2); return b;
}
static __device__ inline float bf2f(unsigned short b) {
    __hip_bfloat16 h; __builtin_memcpy(&h, &b, 2); return __bfloat162float(h);
}

// Convert rows of src [R,768] f32 into fragment-linear bf16 hi/lo chunks.
// Fragment (rg, ks): lane l holds row rg*16+(l&15), k = ks*32+(l>>4)*8 .. +8.
// Chunk layout: dst[(frag*2 + plane)*64 + l], frag = rg*NKS + ks.
static __device__ inline void split_frags(const float* __restrict__ src,
                                          short8* __restrict__ dst, int gt) {
    const int frag = gt >> 6;
    const int l = gt & 63;
    const int rg = frag / NKS;
    const int ks = frag - rg * NKS;
    const int row = rg * 16 + (l & 15);
    const int k0 = ks * 32 + ((l >> 4) << 3);
    const float* xr = src + (size_t)row * HH + k0;
    float xv[8];
    *(float4*)&xv[0] = *(const float4*)xr;
    *(float4*)&xv[4] = *(const float4*)(xr + 4);
    union { unsigned short u[8]; short8 v; } Hc, Lc;
#pragma unroll
    for (int j = 0; j < 8; ++j) {
        const unsigned short hb = f2bf(xv[j]);
        Hc.u[j] = hb;
        Lc.u[j] = f2bf(xv[j] - bf2f(hb));
    }
    dst[(size_t)(frag * 2) * 64 + l]     = Hc.v;
    dst[(size_t)(frag * 2 + 1) * 64 + l] = Lc.v;
}

// K1: blocks [0,768) split gp; [768,1056) split W; [1056,1120) segmean+LN2.
__global__ __launch_bounds__(256) void k_prep(
    const float* __restrict__ gp, const float* __restrict__ Wm,
    const float* __restrict__ hs,
    const float* __restrict__ g2, const float* __restrict__ b2,
    const int* __restrict__ gstart, const int* __restrict__ gend,
    short8* __restrict__ a_ws, short8* __restrict__ b_ws,
    float* __restrict__ sel, float* __restrict__ selnorm)
{
    const int bid = blockIdx.x;
    const int t = threadIdx.x;
    __shared__ float red[3][4];
    __shared__ float sh2[2];

    if (bid < NGPB) {
        split_frags(gp, a_ws, bid * 256 + t);
    } else if (bid < NGPB + NWB) {
        split_frags(Wm, b_ws, (bid - NGPB) * 256 + t);
    } else {
        const int b = bid - (NGPB + NWB);
        const int s0 = gstart[b], e0 = gend[b];
        const float inv = 1.0f / fmaxf((float)(e0 - s0), 1.0f);
        const float* base = hs + (size_t)b * LL * HH;
        const int c0 = t, c1 = t + 256, c2 = t + 512;
        float a[3][4];
#pragma unroll
        for (int j = 0; j < 3; ++j)
#pragma unroll
            for (int u = 0; u < 4; ++u) a[j][u] = 0.f;
        int l = s0;
        for (; l + 4 <= e0; l += 4) {
#pragma unroll
            for (int u = 0; u < 4; ++u) {
                const float* row = base + (size_t)(l + u) * HH;
                a[0][u] += row[c0]; a[1][u] += row[c1]; a[2][u] += row[c2];
            }
        }
        for (; l < e0; ++l) {
            const float* row = base + (size_t)l * HH;
            a[0][0] += row[c0]; a[1][0] += row[c1]; a[2][0] += row[c2];
        }
        float v0 = (a[0][0] + a[0][1] + a[0][2] + a[0][3]) * inv;
        float v1 = (a[1][0] + a[1][1] + a[1][2] + a[1][3]) * inv;
        float v2 = (a[2][0] + a[2][1] + a[2][2] + a[2][3]) * inv;
        float s = v0 + v1 + v2;
        float q = v0 * v0 + v1 * v1 + v2 * v2;
        for (int o = 32; o > 0; o >>= 1) {
            s += __shfl_down(s, o, 64);
            q += __shfl_down(q, o, 64);
        }
        const int lane = t & 63, wid = t >> 6;
        if (lane == 0) { red[0][wid] = s; red[1][wid] = q; }
        __syncthreads();
        if (t == 0) {
            float ts = red[0][0] + red[0][1] + red[0][2] + red[0][3];
            float tq = red[1][0] + red[1][1] + red[1][2] + red[1][3];
            float mu = ts / (float)HH;
            float var = tq / (float)HH - mu * mu;
            sh2[0] = mu; sh2[1] = rsqrtf(var + EPS_LN);
        }
        __syncthreads();
        const float mu = sh2[0], rinv = sh2[1];
        const float y0 = (v0 - mu) * rinv * g2[c0] + b2[c0];
        const float y1 = (v1 - mu) * rinv * g2[c1] + b2[c1];
        const float y2 = (v2 - mu) * rinv * g2[c2] + b2[c2];
        sel[b * HH + c0] = y0; sel[b * HH + c1] = y1; sel[b * HH + c2] = y2;
        float n = y0 * y0 + y1 * y1 + y2 * y2;
        for (int o = 32; o > 0; o >>= 1) n += __shfl_down(n, o, 64);
        if (lane == 0) red[2][wid] = n;
        __syncthreads();
        if (t == 0) selnorm[b] = sqrtf(red[2][0] + red[2][1] + red[2][2] + red[2][3]);
    }
}

// K2: t = gp @ W^T via 3-term bf16-split MFMA. No LDS, no barriers:
// operands are fragment-linear in ws, each load = 64 lanes x 16B contiguous.
// 384 blocks x 2 waves; wave tile = 32m x 64n (2x4 fragments).
#define TRI(ACC, AH, AL, BH, BL) \
    ACC = __builtin_amdgcn_mfma_f32_16x16x32_bf16(AH, BH, ACC, 0, 0, 0); \
    ACC = __builtin_amdgcn_mfma_f32_16x16x32_bf16(AH, BL, ACC, 0, 0, 0); \
    ACC = __builtin_amdgcn_mfma_f32_16x16x32_bf16(AL, BH, ACC, 0, 0, 0);

#define LOADSET(KS, A0H,A0L,A1H,A1L,B0H,B0L,B1H,B1L,B2H,B2L,B3H,B3L) { \
    const int o_ = (KS) * 128; \
    A0H = ba0[o_]; A0L = ba0[o_ + 64]; A1H = ba1[o_]; A1L = ba1[o_ + 64]; \
    B0H = bb0[o_]; B0L = bb0[o_ + 64]; B1H = bb1[o_]; B1L = bb1[o_ + 64]; \
    B2H = bb2[o_]; B2L = bb2[o_ + 64]; B3H = bb3[o_]; B3L = bb3[o_ + 64]; }

#define MFMASET(A0H,A0L,A1H,A1L,B0H,B0L,B1H,B1L,B2H,B2L,B3H,B3L) \
    TRI(acc[0][0], A0H, A0L, B0H, B0L) \
    TRI(acc[0][1], A0H, A0L, B1H, B1L) \
    TRI(acc[0][2], A0H, A0L, B2H, B2L) \
    TRI(acc[0][3], A0H, A0L, B3H, B3L) \
    TRI(acc[1][0], A1H, A1L, B0H, B0L) \
    TRI(acc[1][1], A1H, A1L, B1H, B1L) \
    TRI(acc[1][2], A1H, A1L, B2H, B2L) \
    TRI(acc[1][3], A1H, A1L, B3H, B3L)

__global__ __launch_bounds__(128) void k_gemm(
    const short8* __restrict__ aw, const short8* __restrict__ bw,
    float* __restrict__ tbuf)
{
    const int orig = blockIdx.x;
    const int bid = (orig & 7) * 48 + (orig >> 3);   // XCD swizzle, 384 % 8 == 0
    const int mb = bid / 12;
    const int nb = bid - mb * 12;
    const int wave = threadIdx.x >> 6;
    const int lane = threadIdx.x & 63;

    const int mg0 = mb * 4 + wave * 2;
    const short8* ba0 = aw + (size_t)mg0 * CH_PER_G + lane;
    const short8* ba1 = ba0 + CH_PER_G;
    const short8* bb0 = bw + (size_t)(nb * 4) * CH_PER_G + lane;
    const short8* bb1 = bb0 + CH_PER_G;
    const short8* bb2 = bb1 + CH_PER_G;
    const short8* bb3 = bb2 + CH_PER_G;

    f32x4 acc[2][4] = {};
    short8 a0h,a0l,a1h,a1l,b0h,b0l,b1h,b1l,b2h,b2l,b3h,b3l;
    short8 c0h,c0l,c1h,c1l,d0h,d0l,d1h,d1l,d2h,d2l,d3h,d3l;

    LOADSET(0, a0h,a0l,a1h,a1l,b0h,b0l,b1h,b1l,b2h,b2l,b3h,b3l)
    for (int ks = 0; ks < NKS - 2; ks += 2) {
        LOADSET(ks + 1, c0h,c0l,c1h,c1l,d0h,d0l,d1h,d1l,d2h,d2l,d3h,d3l)
        MFMASET(a0h,a0l,a1h,a1l,b0h,b0l,b1h,b1l,b2h,b2l,b3h,b3l)
        LOADSET(ks + 2, a0h,a0l,a1h,a1l,b0h,b0l,b1h,b1l,b2h,b2l,b3h,b3l)
        MFMASET(c0h,c0l,c1h,c1l,d0h,d0l,d1h,d1l,d2h,d2l,d3h,d3l)
    }
    LOADSET(NKS - 1, c0h,c0l,c1h,c1l,d0h,d0l,d1h,d1l,d2h,d2l,d3h,d3l)
    MFMASET(a0h,a0l,a1h,a1l,b0h,b0l,b1h,b1l,b2h,b2l,b3h,b3l)
    MFMASET(c0h,c0l,c1h,c1l,d0h,d0l,d1h,d1l,d2h,d2l,d3h,d3l)

    // C frag: col = lane&15, row = (lane>>4)*4 + j
    const int wm = mb * 64 + wave * 32;
    const int wn = nb * 64;
    const int r0 = (lane >> 4) * 4;
    const int cc = lane & 15;
#pragma unroll
    for (int mi = 0; mi < 2; ++mi)
#pragma unroll
        for (int ni = 0; ni < 4; ++ni)
#pragma unroll
            for (int j = 0; j < 4; ++j)
                tbuf[(size_t)(wm + mi * 16 + r0 + j) * HH + wn + ni * 16 + cc] =
                    acc[mi][ni][j];
}

// K3: per-row LN(g1,b1) + cosine vs sel. One wave per t-row; bias folded in.
__global__ __launch_bounds__(512) void k_finish(
    const float* __restrict__ tbuf, const float* __restrict__ bias,
    const float* __restrict__ g1, const float* __restrict__ b1,
    const float* __restrict__ sel, const float* __restrict__ selnorm,
    float* __restrict__ out)
{
    const int lane = threadIdx.x & 63;
    const int w = threadIdx.x >> 6;
    const int m = blockIdx.x * 8 + w;
    const int b = m >> 5;
    const float* trow = tbuf + (size_t)m * HH;

    float v[12];
#pragma unroll
    for (int j = 0; j < 12; ++j) {
        const int col = lane + 64 * j;
        v[j] = trow[col] + bias[col];
    }
    float s = 0.f, q = 0.f;
#pragma unroll
    for (int j = 0; j < 12; ++j) { s += v[j]; q = fmaf(v[j], v[j], q); }
    for (int o = 32; o > 0; o >>= 1) {
        s += __shfl_xor(s, o, 64);
        q += __shfl_xor(q, o, 64);
    }
    const float mu = s * (1.0f / (float)HH);
    const float var = q * (1.0f / (float)HH) - mu * mu;
    const float rinv = rsqrtf(var + EPS_LN);

    const float* selb = sel + (size_t)b * HH;
    float d = 0.f, n2 = 0.f;
#pragma unroll
    for (int j = 0; j < 12; ++j) {
        const int col = lane + 64 * j;
        const float y = (v[j] - mu) * rinv * g1[col] + b1[col];
        d = fmaf(y, selb[col], d);
        n2 = fmaf(y, y, n2);
    }
    for (int o = 32; o > 0; o >>= 1) {
        d += __shfl_xor(d, o, 64);
        n2 += __shfl_xor(n2, o, 64);
    }
    if (lane == 0)
        out[m] = d / fmaxf(selnorm[b] * sqrtf(n2), EPS_COS);
}

extern "C" void kernel_launch(void* const* d_in, const int* in_sizes, int n_in,
                              void* d_out, int out_size, void* d_ws, size_t ws_size,
                              hipStream_t stream) {
    const float* hs  = (const float*)d_in[0];
    const float* gp  = (const float*)d_in[1];
    const float* W   = (const float*)d_in[2];
    const float* bia = (const float*)d_in[3];
    const float* g1  = (const float*)d_in[4];
    const float* b1  = (const float*)d_in[5];
    const float* g2  = (const float*)d_in[6];
    const float* b2  = (const float*)d_in[7];
    const int* gs    = (const int*)d_in[8];
    const int* ge    = (const int*)d_in[9];
    float* out = (float*)d_out;

    char* ws = (char*)d_ws;
    short8* a_ws  = (short8*)ws;                                    // 6.29 MB
    short8* b_ws  = (short8*)(ws + (size_t)A_FRAGS * 2 * 64 * 16);  // 2.36 MB
    float* tbuf   = (float*)(ws + (size_t)(A_FRAGS + B_FRAGS) * 2 * 64 * 16); // 6.29 MB
    float* sel     = tbuf + (size_t)MM * HH;
    float* selnorm = sel + (size_t)BB * HH;

    k_prep<<<NGPB + NWB + BB, 256, 0, stream>>>(gp, W, hs, g2, b2, gs, ge,
                                                a_ws, b_ws, sel, selnorm);
    k_gemm<<<384, 128, 0, stream>>>(a_ws, b_ws, tbuf);
    k_finish<<<MM / 8, 512, 0, stream>>>(tbuf, bia, g1, b1, sel, selnorm, out);
}